// Round 2
// baseline (31.857 us; speedup 1.0000x reference)
//
#include <hip/hip_runtime.h>

#define CLAMP_MIN 1e-12f
#define CLAMP_MAX 1e12f

#define BLOCKS 1024
#define WAVES_PER_BLOCK 4

// Fused: per-sample distance (one wave per sample) -> per-block partial ->
// last block reduces partials and writes the mean. Deterministic: no float
// atomics, fixed reduction tree.
__global__ void __launch_bounds__(256) center_loss_fused_kernel(
    const float* __restrict__ x,
    const float* __restrict__ centers,
    const int* __restrict__ labels,
    float* __restrict__ out,
    unsigned int* __restrict__ counter,   // ws[0], zeroed by memsetAsync
    float* __restrict__ partials,         // BLOCKS floats
    int batch, int feat) {
    const int wave = threadIdx.x >> 6;
    const int lane = threadIdx.x & 63;
    const int i = blockIdx.x * WAVES_PER_BLOCK + wave;   // sample index

    __shared__ float swave[WAVES_PER_BLOCK];
    __shared__ bool isLast;

    float part = 0.0f;
    if (i < batch) {
        const float* xr = x + (size_t)i * feat;
        const float* cr = centers + (size_t)labels[i] * feat;
        // feat=512: 2 iterations, 2x float4 per lane per iter.
        for (int k = lane * 4; k < feat; k += 64 * 4) {
            const float4 xv = *reinterpret_cast<const float4*>(xr + k);
            const float4 cv = *reinterpret_cast<const float4*>(cr + k);
            float sxx = xv.x * xv.x + xv.y * xv.y + xv.z * xv.z + xv.w * xv.w;
            float scc = cv.x * cv.x + cv.y * cv.y + cv.z * cv.z + cv.w * cv.w;
            float sxc = xv.x * cv.x + xv.y * cv.y + xv.z * cv.z + xv.w * cv.w;
            part += sxx + scc - 2.0f * sxc;
        }
    }

    // Wave-64 reduction of the per-sample sum.
    #pragma unroll
    for (int off = 32; off > 0; off >>= 1) part += __shfl_down(part, off);

    if (lane == 0) {
        float d = (i < batch) ? fminf(fmaxf(part, CLAMP_MIN), CLAMP_MAX) : 0.0f;
        swave[wave] = d;
    }
    __syncthreads();

    if (threadIdx.x == 0) {
        partials[blockIdx.x] = swave[0] + swave[1] + swave[2] + swave[3];
        __threadfence();  // make partial visible device-wide before signaling
        unsigned int old = atomicAdd(counter, 1u);
        isLast = (old == (unsigned int)(gridDim.x - 1));
    }
    __syncthreads();

    if (isLast) {
        // Reduce BLOCKS partials with 256 threads (all written & visible).
        float s = 0.0f;
        for (int k = threadIdx.x; k < BLOCKS; k += 256) s += partials[k];
        #pragma unroll
        for (int off = 32; off > 0; off >>= 1) s += __shfl_down(s, off);
        __shared__ float sfin[4];
        if (lane == 0) sfin[wave] = s;
        __syncthreads();
        if (threadIdx.x == 0) {
            out[0] = (sfin[0] + sfin[1] + sfin[2] + sfin[3]) / (float)batch;
        }
    }
}

extern "C" void kernel_launch(void* const* d_in, const int* in_sizes, int n_in,
                              void* d_out, int out_size, void* d_ws, size_t ws_size,
                              hipStream_t stream) {
    const float* x       = (const float*)d_in[0];
    const float* centers = (const float*)d_in[1];
    const int*   labels  = (const int*)d_in[2];
    float* out = (float*)d_out;

    const int batch = in_sizes[2];             // 4096
    const int feat  = in_sizes[0] / batch;     // 512

    unsigned int* counter = (unsigned int*)d_ws;
    float* partials = (float*)((char*)d_ws + 256);  // separate cacheline

    hipMemsetAsync(counter, 0, sizeof(unsigned int), stream);
    center_loss_fused_kernel<<<BLOCKS, 256, 0, stream>>>(
        x, centers, labels, out, counter, partials, batch, feat);
}